// Round 14
// baseline (205.067 us; speedup 1.0000x reference)
//
#include <hip/hip_runtime.h>
#include <hip/hip_bf16.h>

typedef __attribute__((ext_vector_type(4))) float  f32x4;
typedef __attribute__((ext_vector_type(8))) short  s16x8;
typedef __attribute__((ext_vector_type(4))) short  s16x4;
typedef unsigned short u16;

constexpr int B_  = 4;
constexpr int S_  = 2048;
constexpr int D_  = 1024;
constexpr int H_  = 16;
constexpr int Dh_ = 64;

// 1/sqrt(Dh) * log2(e) folded into Q at projection time
#define QSCALE 0.18033688f

static __device__ __forceinline__ short fb(float f) {
    __hip_bfloat16 h = __float2bfloat16(f);
    return __builtin_bit_cast(short, h);
}

static __device__ __forceinline__ void gload16(const void* g, void* l) {
    __builtin_amdgcn_global_load_lds(
        (const __attribute__((address_space(1))) unsigned int*)g,
        (__attribute__((address_space(3))) unsigned int*)l, 16, 0, 0);
}

// ---------------------------------------------------------------------------
// f32 -> bf16 convert, 8 elems/thread; blockIdx.y selects array.
// Launch with grid.x * 256 * 8 == element count of each selected array.
// ---------------------------------------------------------------------------
__global__ __launch_bounds__(256)
void cvtW(const float* __restrict__ s0, const float* __restrict__ s1,
          const float* __restrict__ s2, const float* __restrict__ s3,
          u16* __restrict__ d0, u16* __restrict__ d1,
          u16* __restrict__ d2, u16* __restrict__ d3)
{
    const int y = blockIdx.y;
    const float* s = y == 0 ? s0 : (y == 1 ? s1 : (y == 2 ? s2 : s3));
    u16*         d = y == 0 ? d0 : (y == 1 ? d1 : (y == 2 ? d2 : d3));
    long i = ((long)blockIdx.x * 256 + threadIdx.x) * 8;
    f32x4 a = *(const f32x4*)(s + i), b = *(const f32x4*)(s + i + 4);
    s16x8 o;
    #pragma unroll
    for (int j = 0; j < 4; ++j) { o[j] = fb(a[j]); o[4 + j] = fb(b[j]); }
    *(s16x8*)(d + i) = o;
}

// ---------------------------------------------------------------------------
// Fused Q/K/V projection GEMM: grid (64 m-tiles, 8 n-tiles, 3 projections).
// 128x128 tile, BK=32, double-buffered LDS, all-bf16 operands via
// global_load_lds (z=0/1 always; z=2 when VBF, else f32 register-staging).
// z=0: qb16*Wq -> Qp bf16 [B,H,S,Dh] * QSCALE
// z=1: kb16*Wk -> K swizzled tiles [bh][kb][r][swz]
// z=2: v*Wv   -> V^T swizzled tiles [bh][kb][dh][swz]
// ---------------------------------------------------------------------------
template <bool VBF>
__global__ __launch_bounds__(256)
void gemmQKV(const u16* __restrict__ qb16, const u16* __restrict__ kb16,
             const void* __restrict__ vin,
             const u16* __restrict__ WqB, const u16* __restrict__ WkB,
             const u16* __restrict__ WvB,
             u16* __restrict__ Qp, u16* __restrict__ Kt, u16* __restrict__ Vt)
{
    __shared__ u16 As[2][4096];
    __shared__ u16 Bs[2][4096];

    const int z = blockIdx.z;
    const u16* Wb = z == 0 ? WqB : (z == 1 ? WkB : WvB);

    const int m0 = blockIdx.x * 128, n0 = blockIdx.y * 128;
    const int t = threadIdx.x, lane = t & 63, w = t >> 6;
    const int wr = (w >> 1) * 64, wc = (w & 1) * 64;
    const int lr = lane & 15, lg = lane >> 4;

    const int srow = t >> 2;                         // 0..63
    const int cc   = (t & 3) ^ ((t >> 3) & 3);       // swizzled 16B chunk
    const int fcol = (lg ^ ((lr >> 1) & 3)) * 8;     // swizzled read col

    const u16* Brow = Wb + (long)(n0 + srow) * 1024 + cc * 8;
    const bool vReg = (z == 2) && !VBF;              // v register-staging path
    const u16* Arow16 = (z == 0 ? qb16 : (z == 1 ? kb16 : (const u16*)vin))
                        + (long)(m0 + srow) * 1024 + cc * 8;
    const float* Af = (const float*)vin + (long)(m0 + srow) * 1024 + (t & 3) * 8;

    f32x4 acc[4][4] = {};

    // ---- prologue: stage k-step 0 into buffer 0 ----
    if (vReg) {
        f32x4 a0 = *(const f32x4*)(Af);
        f32x4 a1 = *(const f32x4*)(Af + 4);
        f32x4 b0 = *(const f32x4*)(Af + 64 * 1024);
        f32x4 b1 = *(const f32x4*)(Af + 64 * 1024 + 4);
        s16x8 oA, oB;
        #pragma unroll
        for (int j = 0; j < 4; ++j) {
            oA[j] = fb(a0[j]); oA[4 + j] = fb(a1[j]);
            oB[j] = fb(b0[j]); oB[4 + j] = fb(b1[j]);
        }
        *(s16x8*)(&As[0][srow * 32 + cc * 8])        = oA;
        *(s16x8*)(&As[0][(64 + srow) * 32 + cc * 8]) = oB;
    } else {
        gload16(Arow16,             As[0] + w * 512);
        gload16(Arow16 + 64 * 1024, As[0] + 2048 + w * 512);
    }
    gload16(Brow,             Bs[0] + w * 512);
    gload16(Brow + 64 * 1024, Bs[0] + 2048 + w * 512);
    __syncthreads();

    for (int step = 0; step < 32; ++step) {
        const int cur = step & 1, nxt = cur ^ 1;
        const int k1 = (step + 1) * 32;
        const bool more = step + 1 < 32;

        f32x4 a0, a1, b0, b1;
        if (more) {
            if (vReg) {
                a0 = *(const f32x4*)(Af + k1);
                a1 = *(const f32x4*)(Af + k1 + 4);
                b0 = *(const f32x4*)(Af + 64 * 1024 + k1);
                b1 = *(const f32x4*)(Af + 64 * 1024 + k1 + 4);
            } else {
                gload16(Arow16 + k1,             As[nxt] + w * 512);
                gload16(Arow16 + 64 * 1024 + k1, As[nxt] + 2048 + w * 512);
            }
            gload16(Brow + k1,             Bs[nxt] + w * 512);
            gload16(Brow + 64 * 1024 + k1, Bs[nxt] + 2048 + w * 512);
        }

        s16x8 af[4], bfr[4];
        #pragma unroll
        for (int i = 0; i < 4; ++i)
            af[i] = *(const s16x8*)(&As[cur][(wr + i * 16 + lr) * 32 + fcol]);
        #pragma unroll
        for (int i = 0; i < 4; ++i)
            bfr[i] = *(const s16x8*)(&Bs[cur][(wc + i * 16 + lr) * 32 + fcol]);
        #pragma unroll
        for (int mi = 0; mi < 4; ++mi)
            #pragma unroll
            for (int ni = 0; ni < 4; ++ni)
                acc[mi][ni] = __builtin_amdgcn_mfma_f32_16x16x32_bf16(
                    af[mi], bfr[ni], acc[mi][ni], 0, 0, 0);

        if (more && vReg) {
            s16x8 oA, oB;
            #pragma unroll
            for (int j = 0; j < 4; ++j) {
                oA[j] = fb(a0[j]); oA[4 + j] = fb(a1[j]);
                oB[j] = fb(b0[j]); oB[4 + j] = fb(b1[j]);
            }
            *(s16x8*)(&As[nxt][srow * 32 + cc * 8])        = oA;
            *(s16x8*)(&As[nxt][(64 + srow) * 32 + cc * 8]) = oB;
        }
        __syncthreads();
    }

    if (z == 0) {
        #pragma unroll
        for (int mi = 0; mi < 4; ++mi)
            #pragma unroll
            for (int ni = 0; ni < 4; ++ni) {
                int col = n0 + wc + ni * 16 + lr;
                int h = col >> 6, dh = col & 63;
                #pragma unroll
                for (int r = 0; r < 4; ++r) {
                    int row = m0 + wr + mi * 16 + lg * 4 + r;
                    int b = row >> 11, s = row & 2047;
                    Qp[(((long)b * H_ + h) * S_ + s) * Dh_ + dh] =
                        (u16)fb(acc[mi][ni][r] * QSCALE);
                }
            }
    } else if (z == 1) {
        #pragma unroll
        for (int mi = 0; mi < 4; ++mi)
            #pragma unroll
            for (int ni = 0; ni < 4; ++ni) {
                int col = n0 + wc + ni * 16 + lr;
                int h = col >> 6, dh = col & 63;
                #pragma unroll
                for (int r = 0; r < 4; ++r) {
                    int row = m0 + wr + mi * 16 + lg * 4 + r;
                    int b = row >> 11, s = row & 2047;
                    long idx = ((long)(b * H_ + h)) * 131072 + ((long)(s >> 6) << 12)
                             + ((s & 63) << 6) + (((dh >> 3) ^ (s & 7)) << 3) + (dh & 7);
                    Kt[idx] = (u16)fb(acc[mi][ni][r]);
                }
            }
    } else {
        #pragma unroll
        for (int mi = 0; mi < 4; ++mi)
            #pragma unroll
            for (int ni = 0; ni < 4; ++ni) {
                int col = n0 + wc + ni * 16 + lr;
                int h = col >> 6, dh = col & 63;
                int row = m0 + wr + mi * 16 + lg * 4;     // 4 consecutive tokens
                int b = row >> 11, k = row & 2047;
                long idx = ((long)(b * H_ + h)) * 131072 + ((long)(k >> 6) << 12)
                         + (dh << 6) + ((((k >> 3) & 7) ^ (dh & 7)) << 3) + (k & 7);
                union { short h4[4]; unsigned long long u; } pk;
                #pragma unroll
                for (int r = 0; r < 4; ++r) pk.h4[r] = fb(acc[mi][ni][r]);
                *(unsigned long long*)(&Vt[idx]) = pk.u;
            }
    }
}

// ---------------------------------------------------------------------------
// Output projection GEMM: A bf16 [M,1024] (Op), both operands via
// global_load_lds, double-buffered; C f32 [M,1024].
// ---------------------------------------------------------------------------
__global__ __launch_bounds__(256)
void gemmO(const u16* __restrict__ Av, const u16* __restrict__ Wb,
           float* __restrict__ C)
{
    __shared__ u16 As[2][4096];
    __shared__ u16 Bs[2][4096];

    const int m0 = blockIdx.x * 128, n0 = blockIdx.y * 128;
    const int t = threadIdx.x, lane = t & 63, w = t >> 6;
    const int wr = (w >> 1) * 64, wc = (w & 1) * 64;
    const int lr = lane & 15, lg = lane >> 4;

    const int srow = t >> 2;
    const int cc   = (t & 3) ^ ((t >> 3) & 3);
    const int fcol = (lg ^ ((lr >> 1) & 3)) * 8;

    const u16* Brow = Wb + (long)(n0 + srow) * 1024 + cc * 8;
    const u16* Arow = Av + (long)(m0 + srow) * 1024 + cc * 8;

    f32x4 acc[4][4] = {};

    gload16(Arow,             As[0] + w * 512);
    gload16(Arow + 64 * 1024, As[0] + 2048 + w * 512);
    gload16(Brow,             Bs[0] + w * 512);
    gload16(Brow + 64 * 1024, Bs[0] + 2048 + w * 512);
    __syncthreads();

    for (int step = 0; step < 32; ++step) {
        const int cur = step & 1, nxt = cur ^ 1;
        const int k1 = (step + 1) * 32;
        if (step + 1 < 32) {
            gload16(Arow + k1,             As[nxt] + w * 512);
            gload16(Arow + 64 * 1024 + k1, As[nxt] + 2048 + w * 512);
            gload16(Brow + k1,             Bs[nxt] + w * 512);
            gload16(Brow + 64 * 1024 + k1, Bs[nxt] + 2048 + w * 512);
        }
        s16x8 af[4], bfr[4];
        #pragma unroll
        for (int i = 0; i < 4; ++i)
            af[i] = *(const s16x8*)(&As[cur][(wr + i * 16 + lr) * 32 + fcol]);
        #pragma unroll
        for (int i = 0; i < 4; ++i)
            bfr[i] = *(const s16x8*)(&Bs[cur][(wc + i * 16 + lr) * 32 + fcol]);
        #pragma unroll
        for (int mi = 0; mi < 4; ++mi)
            #pragma unroll
            for (int ni = 0; ni < 4; ++ni)
                acc[mi][ni] = __builtin_amdgcn_mfma_f32_16x16x32_bf16(
                    af[mi], bfr[ni], acc[mi][ni], 0, 0, 0);
        __syncthreads();
    }

    #pragma unroll
    for (int mi = 0; mi < 4; ++mi)
        #pragma unroll
        for (int ni = 0; ni < 4; ++ni) {
            int col = n0 + wc + ni * 16 + lr;
            #pragma unroll
            for (int r = 0; r < 4; ++r) {
                int row = m0 + wr + mi * 16 + lg * 4 + r;
                C[(long)row * 1024 + col] = acc[mi][ni][r];
            }
        }
}

// ---------------------------------------------------------------------------
// Causal flash attention (R7 structure + R12 wave-uniform dmask): unchanged.
// ---------------------------------------------------------------------------
__global__ __launch_bounds__(256)
void attn(const u16* __restrict__ Qp, const u16* __restrict__ Kws,
          const u16* __restrict__ Vws, u16* __restrict__ Op)
{
    __shared__ u16 Klds[2][4096];
    __shared__ u16 Vlds[2][4096];

    const int t = threadIdx.x, lane = t & 63, w = t >> 6;   // w 0..3
    const int lr = lane & 15, lg = lane >> 4;
    const int strip = 15 - (int)(blockIdx.x >> 6);          // heavy strips first
    const int bh = blockIdx.x & 63;
    const int b = bh >> 4, h = bh & 15;
    const int q0w = strip * 128 + w * 32;

    const u16* Kb = Kws + (long)bh * 131072;
    const u16* Vb = Vws + (long)bh * 131072;
    const u16* Qbp = Qp + ((long)bh * S_ + q0w) * Dh_;

    const int nkb = (strip + 1) * 2;

    s16x8 qf[2][2];
    #pragma unroll
    for (int i = 0; i < 2; ++i)
        #pragma unroll
        for (int hh = 0; hh < 2; ++hh)
            qf[i][hh] = *(const s16x8*)(Qbp + (i * 16 + lr) * Dh_ + hh * 32 + lg * 8);

    auto stage = [&](int kb, int buf) {
        const long go = (long)kb * 4096 + (2 * w) * 512 + lane * 8;
        gload16(Kb + go,       &Klds[buf][(2 * w) * 512]);
        gload16(Kb + go + 512, &Klds[buf][(2 * w + 1) * 512]);
        gload16(Vb + go,       &Vlds[buf][(2 * w) * 512]);
        gload16(Vb + go + 512, &Vlds[buf][(2 * w + 1) * 512]);
    };

    f32x4 acc[2][4] = {};
    float mrun[2] = { -1e30f, -1e30f }, lrun[2] = { 0.0f, 0.0f };

    stage(0, 0);
    __syncthreads();

    #pragma unroll 1
    for (int kb = 0; kb < nkb; ++kb) {
        const int cur = kb & 1;
        const int k0 = kb * 64;
        if (kb + 1 < nkb) stage(kb + 1, cur ^ 1);
        if (k0 <= q0w + 31) {
            f32x4 st[2][4] = {};
            const int r7 = lr & 7;
            __builtin_amdgcn_s_setprio(1);
            #pragma unroll
            for (int kt = 0; kt < 4; ++kt) {
                const int rb = (kt * 16 + lr) * 64;
                s16x8 kf0 = *(const s16x8*)(&Klds[cur][rb + ((lg ^ r7) << 3)]);
                s16x8 kf1 = *(const s16x8*)(&Klds[cur][rb + (((4 + lg) ^ r7) << 3)]);
                #pragma unroll
                for (int i = 0; i < 2; ++i) {
                    st[i][kt] = __builtin_amdgcn_mfma_f32_16x16x32_bf16(
                        kf0, qf[i][0], st[i][kt], 0, 0, 0);
                    st[i][kt] = __builtin_amdgcn_mfma_f32_16x16x32_bf16(
                        kf1, qf[i][1], st[i][kt], 0, 0, 0);
                }
            }
            __builtin_amdgcn_s_setprio(0);

            const bool dmask = (k0 + 63) > q0w;
            s16x4 pb[2][4];
            #pragma unroll
            for (int i = 0; i < 2; ++i) {
                const int qg = q0w + i * 16 + lr;
                float sv[16];
                if (dmask) {                          // wave-uniform branch
                    #pragma unroll
                    for (int kt = 0; kt < 4; ++kt)
                        #pragma unroll
                        for (int rr = 0; rr < 4; ++rr) {
                            float sc = st[i][kt][rr];
                            if ((k0 + kt * 16 + lg * 4 + rr) > qg) sc = -1e30f;
                            sv[kt * 4 + rr] = sc;
                        }
                } else {
                    #pragma unroll
                    for (int kt = 0; kt < 4; ++kt)
                        #pragma unroll
                        for (int rr = 0; rr < 4; ++rr)
                            sv[kt * 4 + rr] = st[i][kt][rr];
                }
                float t0 = fmaxf(fmaxf(sv[0], sv[1]), sv[2]);
                float t1 = fmaxf(fmaxf(sv[3], sv[4]), sv[5]);
                float t2 = fmaxf(fmaxf(sv[6], sv[7]), sv[8]);
                float t3 = fmaxf(fmaxf(sv[9], sv[10]), sv[11]);
                float t4 = fmaxf(fmaxf(sv[12], sv[13]), sv[14]);
                float tm = fmaxf(fmaxf(fmaxf(t0, t1), t2),
                                 fmaxf(fmaxf(t3, t4), sv[15]));
                tm = fmaxf(tm, __shfl_xor(tm, 16));
                tm = fmaxf(tm, __shfl_xor(tm, 32));
                float mnew = mrun[i];
                if (!__all(tm <= mrun[i] + 8.0f)) {      // T13 defer-max
                    mnew = fmaxf(mrun[i], tm);
                    float f = __builtin_amdgcn_exp2f(mrun[i] - mnew);
                    lrun[i] *= f;
                    #pragma unroll
                    for (int tt = 0; tt < 4; ++tt) acc[i][tt] *= f;
                    mrun[i] = mnew;
                }
                float psum = 0.0f;
                #pragma unroll
                for (int kt = 0; kt < 4; ++kt) {
                    short ph[4];
                    #pragma unroll
                    for (int rr = 0; rr < 4; ++rr) {
                        float p = __builtin_amdgcn_exp2f(sv[kt * 4 + rr] - mnew);
                        psum += p;
                        ph[rr] = fb(p);
                    }
                    pb[i][kt] = (s16x4){ ph[0], ph[1], ph[2], ph[3] };
                }
                lrun[i] += psum;                     // per-lane partial
            }

            __builtin_amdgcn_s_setprio(1);
            #pragma unroll
            for (int kt = 0; kt < 4; ++kt)
                #pragma unroll
                for (int tt = 0; tt < 4; ++tt) {
                    const int rb = (tt * 16 + lr) * 64;
                    const int gsw = (kt * 2 + (lg >> 1)) ^ r7;
                    s16x4 vf = *(const s16x4*)
                        (&Vlds[cur][rb + (gsw << 3) + ((lg & 1) << 2)]);
                    acc[0][tt] = __builtin_amdgcn_mfma_f32_16x16x16bf16_1k(
                        vf, pb[0][kt], acc[0][tt], 0, 0, 0);
                    acc[1][tt] = __builtin_amdgcn_mfma_f32_16x16x16bf16_1k(
                        vf, pb[1][kt], acc[1][tt], 0, 0, 0);
                }
            __builtin_amdgcn_s_setprio(0);
        }
        __syncthreads();
    }

    #pragma unroll
    for (int i = 0; i < 2; ++i) {
        float l = lrun[i];
        l += __shfl_xor(l, 16);
        l += __shfl_xor(l, 32);
        const float inv = 1.0f / l;
        u16* ob = Op + (((long)b * S_ + q0w + i * 16 + lr) * H_ + h) * Dh_;
        #pragma unroll
        for (int tt = 0; tt < 4; ++tt) {
            union { short h4[4]; unsigned long long u; } pk;
            #pragma unroll
            for (int rr = 0; rr < 4; ++rr) pk.h4[rr] = fb(acc[i][tt][rr] * inv);
            *(unsigned long long*)(ob + tt * 16 + lg * 4) = pk.u;
        }
    }
}

// ---------------------------------------------------------------------------
extern "C" void kernel_launch(void* const* d_in, const int* in_sizes, int n_in,
                              void* d_out, int out_size, void* d_ws, size_t ws_size,
                              hipStream_t stream)
{
    const float* q  = (const float*)d_in[0];
    const float* k  = (const float*)d_in[1];
    const float* v  = (const float*)d_in[2];
    // d_in[3] = causal mask — hardcoded
    const float* Wq = (const float*)d_in[4];
    const float* Wk = (const float*)d_in[5];
    const float* Wv = (const float*)d_in[6];
    const float* Wo = (const float*)d_in[7];

    u16* ws = (u16*)d_ws;
    const long NE = (long)B_ * S_ * D_;           // 8388608 elems
    const long WE = (long)D_ * D_;                // 1048576 elems
    u16* Qp  = ws;                                 // [B,H,S,Dh]
    u16* Kws_ = ws + NE;                           // K swizzled tiles
    u16* Vws_ = ws + 2 * NE;                       // V^T swizzled tiles
    u16* Op  = ws + 3 * NE;                        // [B,S,H,Dh] (attn output)

    // q,k bf16 activations live in d_out scratch (exactly 2*NE u16; d_out is
    // fully overwritten by gemmO at the end -> deterministic every call).
    u16* qb16 = (u16*)d_out;
    u16* kb16 = (u16*)d_out + NE;

    const bool needFull = ws_size >= (size_t)(4 * NE + 4 * WE) * 2;  // 75.5MB
    const bool woExtra  = ws_size >= (size_t)(4 * NE + WE) * 2;      // 69.2MB

    dim3 blk(256);
    if (needFull) {
        // v bf16 -> Op region (dead until attn); weights past 4*NE.
        u16* vb16 = Op;
        u16* WqB = ws + 4 * NE;
        u16* WkB = WqB + WE;
        u16* WvB = WqB + 2 * WE;
        u16* WoB = WqB + 3 * WE;
        hipLaunchKernelGGL(cvtW, dim3(4096, 3), blk, 0, stream,
                           q, k, v, v, qb16, kb16, vb16, vb16);
        hipLaunchKernelGGL(cvtW, dim3(512, 4), blk, 0, stream,
                           Wq, Wk, Wv, Wo, WqB, WkB, WvB, WoB);
        hipLaunchKernelGGL((gemmQKV<true>), dim3(64, 8, 3), blk, 0, stream,
                           qb16, kb16, vb16, WqB, WkB, WvB, Qp, Kws_, Vws_);
        hipLaunchKernelGGL(attn, dim3(1024), blk, 0, stream, Qp, Kws_, Vws_, Op);
        hipLaunchKernelGGL(gemmO, dim3(64, 8), blk, 0, stream,
                           Op, WoB, (float*)d_out);
    } else {
        // Fallback: weights in Op region (R12 layout); v stays f32 reg-staged.
        u16* WqB = Op;
        u16* WkB = Op + WE;
        u16* WvB = Op + 2 * WE;
        u16* WoB = woExtra ? (ws + 4 * NE) : Qp;
        hipLaunchKernelGGL(cvtW, dim3(4096, 2), blk, 0, stream,
                           q, k, k, k, qb16, kb16, kb16, kb16);
        if (woExtra) {
            hipLaunchKernelGGL(cvtW, dim3(512, 4), blk, 0, stream,
                               Wq, Wk, Wv, Wo, WqB, WkB, WvB, WoB);
        } else {
            hipLaunchKernelGGL(cvtW, dim3(512, 3), blk, 0, stream,
                               Wq, Wk, Wv, Wo, WqB, WkB, WvB, WoB);
        }
        hipLaunchKernelGGL((gemmQKV<false>), dim3(64, 8, 3), blk, 0, stream,
                           qb16, kb16, v, WqB, WkB, WvB, Qp, Kws_, Vws_);
        hipLaunchKernelGGL(attn, dim3(1024), blk, 0, stream, Qp, Kws_, Vws_, Op);
        if (!woExtra) {
            hipLaunchKernelGGL(cvtW, dim3(512, 1), blk, 0, stream,
                               Wo, Wo, Wo, Wo, WoB, WoB, WoB, WoB);
        }
        hipLaunchKernelGGL(gemmO, dim3(64, 8), blk, 0, stream,
                           Op, WoB, (float*)d_out);
    }
}

// Round 15
// 193.306 us; speedup vs baseline: 1.0608x; 1.0608x over previous
//
#include <hip/hip_runtime.h>
#include <hip/hip_bf16.h>

typedef __attribute__((ext_vector_type(4))) float  f32x4;
typedef __attribute__((ext_vector_type(8))) short  s16x8;
typedef __attribute__((ext_vector_type(4))) short  s16x4;
typedef unsigned short u16;

constexpr int B_  = 4;
constexpr int S_  = 2048;
constexpr int D_  = 1024;
constexpr int H_  = 16;
constexpr int Dh_ = 64;

// 1/sqrt(Dh) * log2(e) folded into Q at projection time
#define QSCALE 0.18033688f

static __device__ __forceinline__ short fb(float f) {
    __hip_bfloat16 h = __float2bfloat16(f);
    return __builtin_bit_cast(short, h);
}

static __device__ __forceinline__ void gload16(const void* g, void* l) {
    __builtin_amdgcn_global_load_lds(
        (const __attribute__((address_space(1))) unsigned int*)g,
        (__attribute__((address_space(3))) unsigned int*)l, 16, 0, 0);
}

// ---------------------------------------------------------------------------
// f32 -> bf16 convert (weights), 8 elems/thread; blockIdx.y selects matrix.
// ---------------------------------------------------------------------------
__global__ __launch_bounds__(256)
void cvtW(const float* __restrict__ s0, const float* __restrict__ s1,
          const float* __restrict__ s2, const float* __restrict__ s3,
          u16* __restrict__ d0, u16* __restrict__ d1,
          u16* __restrict__ d2, u16* __restrict__ d3)
{
    const int y = blockIdx.y;
    const float* s = y == 0 ? s0 : (y == 1 ? s1 : (y == 2 ? s2 : s3));
    u16*         d = y == 0 ? d0 : (y == 1 ? d1 : (y == 2 ? d2 : d3));
    long i = ((long)blockIdx.x * 256 + threadIdx.x) * 8;
    f32x4 a = *(const f32x4*)(s + i), b = *(const f32x4*)(s + i + 4);
    s16x8 o;
    #pragma unroll
    for (int j = 0; j < 4; ++j) { o[j] = fb(a[j]); o[4 + j] = fb(b[j]); }
    *(s16x8*)(d + i) = o;
}

// ---------------------------------------------------------------------------
// Fused Q/K/V projection GEMM (measured best: 114us, 0 LDS conflicts).
// Grid (64, 8, 3). 128x128 tile, BK=32, double-buffered LDS; A f32
// load-early (regs) / cvt+ds_write-late; B bf16 via global_load_lds.
// bf16-in-LDS keeps 64B rows -> conflict-free b128 reads (f32-in-LDS has
// 128B rows = structural bank conflicts, R11; pre-converting A costs more
// than it saves, R13).
// z=0: q*Wq -> Qp bf16 [B,H,S,Dh] * QSCALE
// z=1: k*Wk -> K swizzled tiles [bh][kb][r][swz]
// z=2: v*Wv -> V^T swizzled tiles [bh][kb][dh][swz]
// ---------------------------------------------------------------------------
__global__ __launch_bounds__(256)
void gemmQKV(const float* __restrict__ qin, const float* __restrict__ kin,
             const float* __restrict__ vin,
             const u16* __restrict__ WqB, const u16* __restrict__ WkB,
             const u16* __restrict__ WvB,
             u16* __restrict__ Qp, u16* __restrict__ Kt, u16* __restrict__ Vt)
{
    __shared__ u16 As[2][4096];
    __shared__ u16 Bs[2][4096];

    const int z = blockIdx.z;
    const float* A  = z == 0 ? qin : (z == 1 ? kin : vin);
    const u16*   Wb = z == 0 ? WqB : (z == 1 ? WkB : WvB);

    const int m0 = blockIdx.x * 128, n0 = blockIdx.y * 128;
    const int t = threadIdx.x, lane = t & 63, w = t >> 6;
    const int wr = (w >> 1) * 64, wc = (w & 1) * 64;
    const int lr = lane & 15, lg = lane >> 4;

    const int srow = t >> 2;                         // 0..63
    const int cc   = (t & 3) ^ ((t >> 3) & 3);       // swizzled 16B chunk
    const int fcol = (lg ^ ((lr >> 1) & 3)) * 8;     // swizzled read col

    const u16* Brow = Wb + (long)(n0 + srow) * 1024 + cc * 8;
    const float* Af = A + (long)(m0 + srow) * 1024 + (t & 3) * 8;

    f32x4 acc[4][4] = {};

    // ---- prologue: stage k-step 0 into buffer 0 ----
    {
        f32x4 a0 = *(const f32x4*)(Af);
        f32x4 a1 = *(const f32x4*)(Af + 4);
        f32x4 b0 = *(const f32x4*)(Af + 64 * 1024);
        f32x4 b1 = *(const f32x4*)(Af + 64 * 1024 + 4);
        s16x8 oA, oB;
        #pragma unroll
        for (int j = 0; j < 4; ++j) {
            oA[j] = fb(a0[j]); oA[4 + j] = fb(a1[j]);
            oB[j] = fb(b0[j]); oB[4 + j] = fb(b1[j]);
        }
        *(s16x8*)(&As[0][srow * 32 + cc * 8])        = oA;
        *(s16x8*)(&As[0][(64 + srow) * 32 + cc * 8]) = oB;
    }
    gload16(Brow,             Bs[0] + w * 512);
    gload16(Brow + 64 * 1024, Bs[0] + 2048 + w * 512);
    __syncthreads();

    for (int step = 0; step < 32; ++step) {
        const int cur = step & 1, nxt = cur ^ 1;
        const int k1 = (step + 1) * 32;
        const bool more = step + 1 < 32;

        f32x4 a0, a1, b0, b1;
        if (more) {
            a0 = *(const f32x4*)(Af + k1);
            a1 = *(const f32x4*)(Af + k1 + 4);
            b0 = *(const f32x4*)(Af + 64 * 1024 + k1);
            b1 = *(const f32x4*)(Af + 64 * 1024 + k1 + 4);
            gload16(Brow + k1,             Bs[nxt] + w * 512);
            gload16(Brow + 64 * 1024 + k1, Bs[nxt] + 2048 + w * 512);
        }

        s16x8 af[4], bfr[4];
        #pragma unroll
        for (int i = 0; i < 4; ++i)
            af[i] = *(const s16x8*)(&As[cur][(wr + i * 16 + lr) * 32 + fcol]);
        #pragma unroll
        for (int i = 0; i < 4; ++i)
            bfr[i] = *(const s16x8*)(&Bs[cur][(wc + i * 16 + lr) * 32 + fcol]);
        #pragma unroll
        for (int mi = 0; mi < 4; ++mi)
            #pragma unroll
            for (int ni = 0; ni < 4; ++ni)
                acc[mi][ni] = __builtin_amdgcn_mfma_f32_16x16x32_bf16(
                    af[mi], bfr[ni], acc[mi][ni], 0, 0, 0);

        if (more) {
            s16x8 oA, oB;
            #pragma unroll
            for (int j = 0; j < 4; ++j) {
                oA[j] = fb(a0[j]); oA[4 + j] = fb(a1[j]);
                oB[j] = fb(b0[j]); oB[4 + j] = fb(b1[j]);
            }
            *(s16x8*)(&As[nxt][srow * 32 + cc * 8])        = oA;
            *(s16x8*)(&As[nxt][(64 + srow) * 32 + cc * 8]) = oB;
        }
        __syncthreads();
    }

    if (z == 0) {
        #pragma unroll
        for (int mi = 0; mi < 4; ++mi)
            #pragma unroll
            for (int ni = 0; ni < 4; ++ni) {
                int col = n0 + wc + ni * 16 + lr;
                int h = col >> 6, dh = col & 63;
                #pragma unroll
                for (int r = 0; r < 4; ++r) {
                    int row = m0 + wr + mi * 16 + lg * 4 + r;
                    int b = row >> 11, s = row & 2047;
                    Qp[(((long)b * H_ + h) * S_ + s) * Dh_ + dh] =
                        (u16)fb(acc[mi][ni][r] * QSCALE);
                }
            }
    } else if (z == 1) {
        #pragma unroll
        for (int mi = 0; mi < 4; ++mi)
            #pragma unroll
            for (int ni = 0; ni < 4; ++ni) {
                int col = n0 + wc + ni * 16 + lr;
                int h = col >> 6, dh = col & 63;
                #pragma unroll
                for (int r = 0; r < 4; ++r) {
                    int row = m0 + wr + mi * 16 + lg * 4 + r;
                    int b = row >> 11, s = row & 2047;
                    long idx = ((long)(b * H_ + h)) * 131072 + ((long)(s >> 6) << 12)
                             + ((s & 63) << 6) + (((dh >> 3) ^ (s & 7)) << 3) + (dh & 7);
                    Kt[idx] = (u16)fb(acc[mi][ni][r]);
                }
            }
    } else {
        #pragma unroll
        for (int mi = 0; mi < 4; ++mi)
            #pragma unroll
            for (int ni = 0; ni < 4; ++ni) {
                int col = n0 + wc + ni * 16 + lr;
                int h = col >> 6, dh = col & 63;
                int row = m0 + wr + mi * 16 + lg * 4;     // 4 consecutive tokens
                int b = row >> 11, k = row & 2047;
                long idx = ((long)(b * H_ + h)) * 131072 + ((long)(k >> 6) << 12)
                         + (dh << 6) + ((((k >> 3) & 7) ^ (dh & 7)) << 3) + (k & 7);
                union { short h4[4]; unsigned long long u; } pk;
                #pragma unroll
                for (int r = 0; r < 4; ++r) pk.h4[r] = fb(acc[mi][ni][r]);
                *(unsigned long long*)(&Vt[idx]) = pk.u;
            }
    }
}

// ---------------------------------------------------------------------------
// Output projection GEMM: A bf16 [M,1024] (Op), both operands via
// global_load_lds, double-buffered; C f32 [M,1024]. (measured ~25us)
// ---------------------------------------------------------------------------
__global__ __launch_bounds__(256)
void gemmO(const u16* __restrict__ Av, const u16* __restrict__ Wb,
           float* __restrict__ C)
{
    __shared__ u16 As[2][4096];
    __shared__ u16 Bs[2][4096];

    const int m0 = blockIdx.x * 128, n0 = blockIdx.y * 128;
    const int t = threadIdx.x, lane = t & 63, w = t >> 6;
    const int wr = (w >> 1) * 64, wc = (w & 1) * 64;
    const int lr = lane & 15, lg = lane >> 4;

    const int srow = t >> 2;
    const int cc   = (t & 3) ^ ((t >> 3) & 3);
    const int fcol = (lg ^ ((lr >> 1) & 3)) * 8;

    const u16* Brow = Wb + (long)(n0 + srow) * 1024 + cc * 8;
    const u16* Arow = Av + (long)(m0 + srow) * 1024 + cc * 8;

    f32x4 acc[4][4] = {};

    gload16(Arow,             As[0] + w * 512);
    gload16(Arow + 64 * 1024, As[0] + 2048 + w * 512);
    gload16(Brow,             Bs[0] + w * 512);
    gload16(Brow + 64 * 1024, Bs[0] + 2048 + w * 512);
    __syncthreads();

    for (int step = 0; step < 32; ++step) {
        const int cur = step & 1, nxt = cur ^ 1;
        const int k1 = (step + 1) * 32;
        if (step + 1 < 32) {
            gload16(Arow + k1,             As[nxt] + w * 512);
            gload16(Arow + 64 * 1024 + k1, As[nxt] + 2048 + w * 512);
            gload16(Brow + k1,             Bs[nxt] + w * 512);
            gload16(Brow + 64 * 1024 + k1, Bs[nxt] + 2048 + w * 512);
        }
        s16x8 af[4], bfr[4];
        #pragma unroll
        for (int i = 0; i < 4; ++i)
            af[i] = *(const s16x8*)(&As[cur][(wr + i * 16 + lr) * 32 + fcol]);
        #pragma unroll
        for (int i = 0; i < 4; ++i)
            bfr[i] = *(const s16x8*)(&Bs[cur][(wc + i * 16 + lr) * 32 + fcol]);
        #pragma unroll
        for (int mi = 0; mi < 4; ++mi)
            #pragma unroll
            for (int ni = 0; ni < 4; ++ni)
                acc[mi][ni] = __builtin_amdgcn_mfma_f32_16x16x32_bf16(
                    af[mi], bfr[ni], acc[mi][ni], 0, 0, 0);
        __syncthreads();
    }

    #pragma unroll
    for (int mi = 0; mi < 4; ++mi)
        #pragma unroll
        for (int ni = 0; ni < 4; ++ni) {
            int col = n0 + wc + ni * 16 + lr;
            #pragma unroll
            for (int r = 0; r < 4; ++r) {
                int row = m0 + wr + mi * 16 + lg * 4 + r;
                C[(long)row * 1024 + col] = acc[mi][ni][r];
            }
        }
}

// ---------------------------------------------------------------------------
// Causal flash attention (R7 structure + R12 wave-uniform dmask; measured
// best ~86us): 1 block = 4 waves = 128 q-rows of one (b,h); grid 1024,
// heavy strips first; double-buffered K/V tiles via global_load_lds from
// pre-swizzled workspace.
// ---------------------------------------------------------------------------
__global__ __launch_bounds__(256)
void attn(const u16* __restrict__ Qp, const u16* __restrict__ Kws,
          const u16* __restrict__ Vws, u16* __restrict__ Op)
{
    __shared__ u16 Klds[2][4096];
    __shared__ u16 Vlds[2][4096];

    const int t = threadIdx.x, lane = t & 63, w = t >> 6;   // w 0..3
    const int lr = lane & 15, lg = lane >> 4;
    const int strip = 15 - (int)(blockIdx.x >> 6);          // heavy strips first
    const int bh = blockIdx.x & 63;
    const int b = bh >> 4, h = bh & 15;
    const int q0w = strip * 128 + w * 32;

    const u16* Kb = Kws + (long)bh * 131072;
    const u16* Vb = Vws + (long)bh * 131072;
    const u16* Qbp = Qp + ((long)bh * S_ + q0w) * Dh_;

    const int nkb = (strip + 1) * 2;

    s16x8 qf[2][2];
    #pragma unroll
    for (int i = 0; i < 2; ++i)
        #pragma unroll
        for (int hh = 0; hh < 2; ++hh)
            qf[i][hh] = *(const s16x8*)(Qbp + (i * 16 + lr) * Dh_ + hh * 32 + lg * 8);

    auto stage = [&](int kb, int buf) {
        const long go = (long)kb * 4096 + (2 * w) * 512 + lane * 8;
        gload16(Kb + go,       &Klds[buf][(2 * w) * 512]);
        gload16(Kb + go + 512, &Klds[buf][(2 * w + 1) * 512]);
        gload16(Vb + go,       &Vlds[buf][(2 * w) * 512]);
        gload16(Vb + go + 512, &Vlds[buf][(2 * w + 1) * 512]);
    };

    f32x4 acc[2][4] = {};
    float mrun[2] = { -1e30f, -1e30f }, lrun[2] = { 0.0f, 0.0f };

    stage(0, 0);
    __syncthreads();

    #pragma unroll 1
    for (int kb = 0; kb < nkb; ++kb) {
        const int cur = kb & 1;
        const int k0 = kb * 64;
        if (kb + 1 < nkb) stage(kb + 1, cur ^ 1);
        if (k0 <= q0w + 31) {
            f32x4 st[2][4] = {};
            const int r7 = lr & 7;
            __builtin_amdgcn_s_setprio(1);
            #pragma unroll
            for (int kt = 0; kt < 4; ++kt) {
                const int rb = (kt * 16 + lr) * 64;
                s16x8 kf0 = *(const s16x8*)(&Klds[cur][rb + ((lg ^ r7) << 3)]);
                s16x8 kf1 = *(const s16x8*)(&Klds[cur][rb + (((4 + lg) ^ r7) << 3)]);
                #pragma unroll
                for (int i = 0; i < 2; ++i) {
                    st[i][kt] = __builtin_amdgcn_mfma_f32_16x16x32_bf16(
                        kf0, qf[i][0], st[i][kt], 0, 0, 0);
                    st[i][kt] = __builtin_amdgcn_mfma_f32_16x16x32_bf16(
                        kf1, qf[i][1], st[i][kt], 0, 0, 0);
                }
            }
            __builtin_amdgcn_s_setprio(0);

            const bool dmask = (k0 + 63) > q0w;
            s16x4 pb[2][4];
            #pragma unroll
            for (int i = 0; i < 2; ++i) {
                const int qg = q0w + i * 16 + lr;
                float sv[16];
                if (dmask) {                          // wave-uniform branch
                    #pragma unroll
                    for (int kt = 0; kt < 4; ++kt)
                        #pragma unroll
                        for (int rr = 0; rr < 4; ++rr) {
                            float sc = st[i][kt][rr];
                            if ((k0 + kt * 16 + lg * 4 + rr) > qg) sc = -1e30f;
                            sv[kt * 4 + rr] = sc;
                        }
                } else {
                    #pragma unroll
                    for (int kt = 0; kt < 4; ++kt)
                        #pragma unroll
                        for (int rr = 0; rr < 4; ++rr)
                            sv[kt * 4 + rr] = st[i][kt][rr];
                }
                float t0 = fmaxf(fmaxf(sv[0], sv[1]), sv[2]);
                float t1 = fmaxf(fmaxf(sv[3], sv[4]), sv[5]);
                float t2 = fmaxf(fmaxf(sv[6], sv[7]), sv[8]);
                float t3 = fmaxf(fmaxf(sv[9], sv[10]), sv[11]);
                float t4 = fmaxf(fmaxf(sv[12], sv[13]), sv[14]);
                float tm = fmaxf(fmaxf(fmaxf(t0, t1), t2),
                                 fmaxf(fmaxf(t3, t4), sv[15]));
                tm = fmaxf(tm, __shfl_xor(tm, 16));
                tm = fmaxf(tm, __shfl_xor(tm, 32));
                float mnew = mrun[i];
                if (!__all(tm <= mrun[i] + 8.0f)) {      // T13 defer-max
                    mnew = fmaxf(mrun[i], tm);
                    float f = __builtin_amdgcn_exp2f(mrun[i] - mnew);
                    lrun[i] *= f;
                    #pragma unroll
                    for (int tt = 0; tt < 4; ++tt) acc[i][tt] *= f;
                    mrun[i] = mnew;
                }
                float psum = 0.0f;
                #pragma unroll
                for (int kt = 0; kt < 4; ++kt) {
                    short ph[4];
                    #pragma unroll
                    for (int rr = 0; rr < 4; ++rr) {
                        float p = __builtin_amdgcn_exp2f(sv[kt * 4 + rr] - mnew);
                        psum += p;
                        ph[rr] = fb(p);
                    }
                    pb[i][kt] = (s16x4){ ph[0], ph[1], ph[2], ph[3] };
                }
                lrun[i] += psum;                     // per-lane partial
            }

            __builtin_amdgcn_s_setprio(1);
            #pragma unroll
            for (int kt = 0; kt < 4; ++kt)
                #pragma unroll
                for (int tt = 0; tt < 4; ++tt) {
                    const int rb = (tt * 16 + lr) * 64;
                    const int gsw = (kt * 2 + (lg >> 1)) ^ r7;
                    s16x4 vf = *(const s16x4*)
                        (&Vlds[cur][rb + (gsw << 3) + ((lg & 1) << 2)]);
                    acc[0][tt] = __builtin_amdgcn_mfma_f32_16x16x16bf16_1k(
                        vf, pb[0][kt], acc[0][tt], 0, 0, 0);
                    acc[1][tt] = __builtin_amdgcn_mfma_f32_16x16x16bf16_1k(
                        vf, pb[1][kt], acc[1][tt], 0, 0, 0);
                }
            __builtin_amdgcn_s_setprio(0);
        }
        __syncthreads();
    }

    #pragma unroll
    for (int i = 0; i < 2; ++i) {
        float l = lrun[i];
        l += __shfl_xor(l, 16);
        l += __shfl_xor(l, 32);
        const float inv = 1.0f / l;
        u16* ob = Op + (((long)b * S_ + q0w + i * 16 + lr) * H_ + h) * Dh_;
        #pragma unroll
        for (int tt = 0; tt < 4; ++tt) {
            union { short h4[4]; unsigned long long u; } pk;
            #pragma unroll
            for (int rr = 0; rr < 4; ++rr) pk.h4[rr] = fb(acc[i][tt][rr] * inv);
            *(unsigned long long*)(ob + tt * 16 + lg * 4) = pk.u;
        }
    }
}

// ---------------------------------------------------------------------------
extern "C" void kernel_launch(void* const* d_in, const int* in_sizes, int n_in,
                              void* d_out, int out_size, void* d_ws, size_t ws_size,
                              hipStream_t stream)
{
    const float* q  = (const float*)d_in[0];
    const float* k  = (const float*)d_in[1];
    const float* v  = (const float*)d_in[2];
    // d_in[3] = causal mask — hardcoded
    const float* Wq = (const float*)d_in[4];
    const float* Wk = (const float*)d_in[5];
    const float* Wv = (const float*)d_in[6];
    const float* Wo = (const float*)d_in[7];

    u16* ws = (u16*)d_ws;
    const long NE = (long)B_ * S_ * D_;           // 8388608 elems
    const long WE = (long)D_ * D_;                // 1048576 elems
    u16* Qp  = ws;                                 // [B,H,S,Dh]
    u16* Kws_ = ws + NE;                           // K swizzled tiles
    u16* Vws_ = ws + 2 * NE;                       // V^T swizzled tiles
    u16* Op  = ws + 3 * NE;                        // [B,S,H,Dh]
    u16* WqB = Op;            // dead before attn writes Op
    u16* WkB = Op + WE;
    u16* WvB = Op + 2 * WE;

    // Wo-bf16: spare region past 4*NE if ws allows (single up-front cvt);
    // else fall back to Qp after attn (extra launch).
    const bool woExtra = ws_size >= (size_t)(4 * NE + WE) * 2;
    u16* WoB = woExtra ? (ws + 4 * NE) : Qp;

    dim3 blk(256);
    if (woExtra) {
        hipLaunchKernelGGL(cvtW, dim3(512, 4), blk, 0, stream,
                           Wq, Wk, Wv, Wo, WqB, WkB, WvB, WoB);
    } else {
        hipLaunchKernelGGL(cvtW, dim3(512, 3), blk, 0, stream,
                           Wq, Wk, Wv, Wo, WqB, WkB, WvB, WoB);
    }
    hipLaunchKernelGGL(gemmQKV, dim3(64, 8, 3), blk, 0, stream,
                       q, k, v, WqB, WkB, WvB, Qp, Kws_, Vws_);
    hipLaunchKernelGGL(attn, dim3(1024), blk, 0, stream, Qp, Kws_, Vws_, Op);
    if (!woExtra) {
        hipLaunchKernelGGL(cvtW, dim3(512, 1), blk, 0, stream,
                           Wo, Wo, Wo, Wo, WoB, WoB, WoB, WoB);
    }
    hipLaunchKernelGGL(gemmO, dim3(64, 8), blk, 0, stream, Op, WoB, (float*)d_out);
}

// Round 16
// 187.184 us; speedup vs baseline: 1.0955x; 1.0327x over previous
//
#include <hip/hip_runtime.h>
#include <hip/hip_bf16.h>

typedef __attribute__((ext_vector_type(4))) float  f32x4;
typedef __attribute__((ext_vector_type(8))) short  s16x8;
typedef __attribute__((ext_vector_type(4))) short  s16x4;
typedef unsigned short u16;

constexpr int B_  = 4;
constexpr int S_  = 2048;
constexpr int D_  = 1024;
constexpr int H_  = 16;
constexpr int Dh_ = 64;

// 1/sqrt(Dh) * log2(e) folded into Q at projection time
#define QSCALE 0.18033688f

static __device__ __forceinline__ short fb(float f) {
    __hip_bfloat16 h = __float2bfloat16(f);
    return __builtin_bit_cast(short, h);
}

static __device__ __forceinline__ void gload16(const void* g, void* l) {
    __builtin_amdgcn_global_load_lds(
        (const __attribute__((address_space(1))) unsigned int*)g,
        (__attribute__((address_space(3))) unsigned int*)l, 16, 0, 0);
}

// ---------------------------------------------------------------------------
// f32 -> bf16 convert (weights), 8 elems/thread; blockIdx.y selects matrix.
// ---------------------------------------------------------------------------
__global__ __launch_bounds__(256)
void cvtW(const float* __restrict__ s0, const float* __restrict__ s1,
          const float* __restrict__ s2, const float* __restrict__ s3,
          u16* __restrict__ d0, u16* __restrict__ d1,
          u16* __restrict__ d2, u16* __restrict__ d3)
{
    const int y = blockIdx.y;
    const float* s = y == 0 ? s0 : (y == 1 ? s1 : (y == 2 ? s2 : s3));
    u16*         d = y == 0 ? d0 : (y == 1 ? d1 : (y == 2 ? d2 : d3));
    long i = ((long)blockIdx.x * 256 + threadIdx.x) * 8;
    f32x4 a = *(const f32x4*)(s + i), b = *(const f32x4*)(s + i + 4);
    s16x8 o;
    #pragma unroll
    for (int j = 0; j < 4; ++j) { o[j] = fb(a[j]); o[4 + j] = fb(b[j]); }
    *(s16x8*)(d + i) = o;
}

// ---------------------------------------------------------------------------
// Fused Q/K/V projection GEMM v4: 128x256 tile, 8 waves (512 thr), BK=32,
// double-buffered. A f32 load-early (regs) / cvt+ds_write-late, staged ONCE
// per block and consumed by 2x the MFMA of the 128x128 version (staging VALU
// per MFMA halves). B bf16 via global_load_lds (2 rounds of 128 rows).
// LDS 48KB -> 3 blocks/CU (24 waves/CU potential); grid (64,4,3) = 3/CU.
// Per-thread state unchanged from v3 (VGPR ~80).
// z=0: q*Wq -> Qp bf16 [B,H,S,Dh] * QSCALE
// z=1: k*Wk -> K swizzled tiles [bh][kb][r][swz]
// z=2: v*Wv -> V^T swizzled tiles [bh][kb][dh][swz]
// ---------------------------------------------------------------------------
__global__ __launch_bounds__(512)
void gemmQKV(const float* __restrict__ qin, const float* __restrict__ kin,
             const float* __restrict__ vin,
             const u16* __restrict__ WqB, const u16* __restrict__ WkB,
             const u16* __restrict__ WvB,
             u16* __restrict__ Qp, u16* __restrict__ Kt, u16* __restrict__ Vt)
{
    __shared__ u16 As[2][4096];      // 128 rows x 32 bf16 (16KB)
    __shared__ u16 Bs[2][8192];      // 256 rows x 32 bf16 (32KB)

    const int z = blockIdx.z;
    const float* A  = z == 0 ? qin : (z == 1 ? kin : vin);
    const u16*   Wb = z == 0 ? WqB : (z == 1 ? WkB : WvB);

    const int m0 = blockIdx.x * 128, n0 = blockIdx.y * 256;
    const int t = threadIdx.x, lane = t & 63, w = t >> 6;   // w 0..7
    const int wr = (w >> 2) * 64, wc = (w & 3) * 64;
    const int lr = lane & 15, lg = lane >> 4;

    const int srow = t >> 2;                         // 0..127
    const int cc   = (t & 3) ^ ((t >> 3) & 3);       // swizzled 16B chunk
    const int fcol = (lg ^ ((lr >> 1) & 3)) * 8;     // swizzled read col

    const u16* Brow = Wb + (long)(n0 + srow) * 1024 + cc * 8;
    const float* Af = A + (long)(m0 + srow) * 1024 + (t & 3) * 8;

    f32x4 acc[4][4] = {};

    // ---- prologue: stage k-step 0 into buffer 0 ----
    {
        f32x4 a0 = *(const f32x4*)(Af);
        f32x4 a1 = *(const f32x4*)(Af + 4);
        s16x8 oA;
        #pragma unroll
        for (int j = 0; j < 4; ++j) { oA[j] = fb(a0[j]); oA[4 + j] = fb(a1[j]); }
        *(s16x8*)(&As[0][srow * 32 + cc * 8]) = oA;
    }
    gload16(Brow,              Bs[0] + w * 512);
    gload16(Brow + 128 * 1024, Bs[0] + 4096 + w * 512);
    __syncthreads();

    for (int step = 0; step < 32; ++step) {
        const int cur = step & 1, nxt = cur ^ 1;
        const int k1 = (step + 1) * 32;
        const bool more = step + 1 < 32;

        f32x4 a0, a1;
        if (more) {
            a0 = *(const f32x4*)(Af + k1);
            a1 = *(const f32x4*)(Af + k1 + 4);
            gload16(Brow + k1,              Bs[nxt] + w * 512);
            gload16(Brow + 128 * 1024 + k1, Bs[nxt] + 4096 + w * 512);
        }

        s16x8 af[4], bfr[4];
        #pragma unroll
        for (int i = 0; i < 4; ++i)
            af[i] = *(const s16x8*)(&As[cur][(wr + i * 16 + lr) * 32 + fcol]);
        #pragma unroll
        for (int i = 0; i < 4; ++i)
            bfr[i] = *(const s16x8*)(&Bs[cur][(wc + i * 16 + lr) * 32 + fcol]);
        #pragma unroll
        for (int mi = 0; mi < 4; ++mi)
            #pragma unroll
            for (int ni = 0; ni < 4; ++ni)
                acc[mi][ni] = __builtin_amdgcn_mfma_f32_16x16x32_bf16(
                    af[mi], bfr[ni], acc[mi][ni], 0, 0, 0);

        if (more) {
            s16x8 oA;
            #pragma unroll
            for (int j = 0; j < 4; ++j) { oA[j] = fb(a0[j]); oA[4 + j] = fb(a1[j]); }
            *(s16x8*)(&As[nxt][srow * 32 + cc * 8]) = oA;
        }
        __syncthreads();
    }

    if (z == 0) {
        #pragma unroll
        for (int mi = 0; mi < 4; ++mi)
            #pragma unroll
            for (int ni = 0; ni < 4; ++ni) {
                int col = n0 + wc + ni * 16 + lr;
                int h = col >> 6, dh = col & 63;
                #pragma unroll
                for (int r = 0; r < 4; ++r) {
                    int row = m0 + wr + mi * 16 + lg * 4 + r;
                    int b = row >> 11, s = row & 2047;
                    Qp[(((long)b * H_ + h) * S_ + s) * Dh_ + dh] =
                        (u16)fb(acc[mi][ni][r] * QSCALE);
                }
            }
    } else if (z == 1) {
        #pragma unroll
        for (int mi = 0; mi < 4; ++mi)
            #pragma unroll
            for (int ni = 0; ni < 4; ++ni) {
                int col = n0 + wc + ni * 16 + lr;
                int h = col >> 6, dh = col & 63;
                #pragma unroll
                for (int r = 0; r < 4; ++r) {
                    int row = m0 + wr + mi * 16 + lg * 4 + r;
                    int b = row >> 11, s = row & 2047;
                    long idx = ((long)(b * H_ + h)) * 131072 + ((long)(s >> 6) << 12)
                             + ((s & 63) << 6) + (((dh >> 3) ^ (s & 7)) << 3) + (dh & 7);
                    Kt[idx] = (u16)fb(acc[mi][ni][r]);
                }
            }
    } else {
        #pragma unroll
        for (int mi = 0; mi < 4; ++mi)
            #pragma unroll
            for (int ni = 0; ni < 4; ++ni) {
                int col = n0 + wc + ni * 16 + lr;
                int h = col >> 6, dh = col & 63;
                int row = m0 + wr + mi * 16 + lg * 4;     // 4 consecutive tokens
                int b = row >> 11, k = row & 2047;
                long idx = ((long)(b * H_ + h)) * 131072 + ((long)(k >> 6) << 12)
                         + (dh << 6) + ((((k >> 3) & 7) ^ (dh & 7)) << 3) + (k & 7);
                union { short h4[4]; unsigned long long u; } pk;
                #pragma unroll
                for (int r = 0; r < 4; ++r) pk.h4[r] = fb(acc[mi][ni][r]);
                *(unsigned long long*)(&Vt[idx]) = pk.u;
            }
    }
}

// ---------------------------------------------------------------------------
// Output projection GEMM: A bf16 [M,1024] (Op), both operands via
// global_load_lds, double-buffered; C f32 [M,1024]. (measured ~25us)
// ---------------------------------------------------------------------------
__global__ __launch_bounds__(256)
void gemmO(const u16* __restrict__ Av, const u16* __restrict__ Wb,
           float* __restrict__ C)
{
    __shared__ u16 As[2][4096];
    __shared__ u16 Bs[2][4096];

    const int m0 = blockIdx.x * 128, n0 = blockIdx.y * 128;
    const int t = threadIdx.x, lane = t & 63, w = t >> 6;
    const int wr = (w >> 1) * 64, wc = (w & 1) * 64;
    const int lr = lane & 15, lg = lane >> 4;

    const int srow = t >> 2;
    const int cc   = (t & 3) ^ ((t >> 3) & 3);
    const int fcol = (lg ^ ((lr >> 1) & 3)) * 8;

    const u16* Brow = Wb + (long)(n0 + srow) * 1024 + cc * 8;
    const u16* Arow = Av + (long)(m0 + srow) * 1024 + cc * 8;

    f32x4 acc[4][4] = {};

    gload16(Arow,             As[0] + w * 512);
    gload16(Arow + 64 * 1024, As[0] + 2048 + w * 512);
    gload16(Brow,             Bs[0] + w * 512);
    gload16(Brow + 64 * 1024, Bs[0] + 2048 + w * 512);
    __syncthreads();

    for (int step = 0; step < 32; ++step) {
        const int cur = step & 1, nxt = cur ^ 1;
        const int k1 = (step + 1) * 32;
        if (step + 1 < 32) {
            gload16(Arow + k1,             As[nxt] + w * 512);
            gload16(Arow + 64 * 1024 + k1, As[nxt] + 2048 + w * 512);
            gload16(Brow + k1,             Bs[nxt] + w * 512);
            gload16(Brow + 64 * 1024 + k1, Bs[nxt] + 2048 + w * 512);
        }
        s16x8 af[4], bfr[4];
        #pragma unroll
        for (int i = 0; i < 4; ++i)
            af[i] = *(const s16x8*)(&As[cur][(wr + i * 16 + lr) * 32 + fcol]);
        #pragma unroll
        for (int i = 0; i < 4; ++i)
            bfr[i] = *(const s16x8*)(&Bs[cur][(wc + i * 16 + lr) * 32 + fcol]);
        #pragma unroll
        for (int mi = 0; mi < 4; ++mi)
            #pragma unroll
            for (int ni = 0; ni < 4; ++ni)
                acc[mi][ni] = __builtin_amdgcn_mfma_f32_16x16x32_bf16(
                    af[mi], bfr[ni], acc[mi][ni], 0, 0, 0);
        __syncthreads();
    }

    #pragma unroll
    for (int mi = 0; mi < 4; ++mi)
        #pragma unroll
        for (int ni = 0; ni < 4; ++ni) {
            int col = n0 + wc + ni * 16 + lr;
            #pragma unroll
            for (int r = 0; r < 4; ++r) {
                int row = m0 + wr + mi * 16 + lg * 4 + r;
                C[(long)row * 1024 + col] = acc[mi][ni][r];
            }
        }
}

// ---------------------------------------------------------------------------
// Causal flash attention (R7 structure + R12 wave-uniform dmask; ~86us).
// ---------------------------------------------------------------------------
__global__ __launch_bounds__(256)
void attn(const u16* __restrict__ Qp, const u16* __restrict__ Kws,
          const u16* __restrict__ Vws, u16* __restrict__ Op)
{
    __shared__ u16 Klds[2][4096];
    __shared__ u16 Vlds[2][4096];

    const int t = threadIdx.x, lane = t & 63, w = t >> 6;   // w 0..3
    const int lr = lane & 15, lg = lane >> 4;
    const int strip = 15 - (int)(blockIdx.x >> 6);          // heavy strips first
    const int bh = blockIdx.x & 63;
    const int b = bh >> 4, h = bh & 15;
    const int q0w = strip * 128 + w * 32;

    const u16* Kb = Kws + (long)bh * 131072;
    const u16* Vb = Vws + (long)bh * 131072;
    const u16* Qbp = Qp + ((long)bh * S_ + q0w) * Dh_;

    const int nkb = (strip + 1) * 2;

    s16x8 qf[2][2];
    #pragma unroll
    for (int i = 0; i < 2; ++i)
        #pragma unroll
        for (int hh = 0; hh < 2; ++hh)
            qf[i][hh] = *(const s16x8*)(Qbp + (i * 16 + lr) * Dh_ + hh * 32 + lg * 8);

    auto stage = [&](int kb, int buf) {
        const long go = (long)kb * 4096 + (2 * w) * 512 + lane * 8;
        gload16(Kb + go,       &Klds[buf][(2 * w) * 512]);
        gload16(Kb + go + 512, &Klds[buf][(2 * w + 1) * 512]);
        gload16(Vb + go,       &Vlds[buf][(2 * w) * 512]);
        gload16(Vb + go + 512, &Vlds[buf][(2 * w + 1) * 512]);
    };

    f32x4 acc[2][4] = {};
    float mrun[2] = { -1e30f, -1e30f }, lrun[2] = { 0.0f, 0.0f };

    stage(0, 0);
    __syncthreads();

    #pragma unroll 1
    for (int kb = 0; kb < nkb; ++kb) {
        const int cur = kb & 1;
        const int k0 = kb * 64;
        if (kb + 1 < nkb) stage(kb + 1, cur ^ 1);
        if (k0 <= q0w + 31) {
            f32x4 st[2][4] = {};
            const int r7 = lr & 7;
            __builtin_amdgcn_s_setprio(1);
            #pragma unroll
            for (int kt = 0; kt < 4; ++kt) {
                const int rb = (kt * 16 + lr) * 64;
                s16x8 kf0 = *(const s16x8*)(&Klds[cur][rb + ((lg ^ r7) << 3)]);
                s16x8 kf1 = *(const s16x8*)(&Klds[cur][rb + (((4 + lg) ^ r7) << 3)]);
                #pragma unroll
                for (int i = 0; i < 2; ++i) {
                    st[i][kt] = __builtin_amdgcn_mfma_f32_16x16x32_bf16(
                        kf0, qf[i][0], st[i][kt], 0, 0, 0);
                    st[i][kt] = __builtin_amdgcn_mfma_f32_16x16x32_bf16(
                        kf1, qf[i][1], st[i][kt], 0, 0, 0);
                }
            }
            __builtin_amdgcn_s_setprio(0);

            const bool dmask = (k0 + 63) > q0w;
            s16x4 pb[2][4];
            #pragma unroll
            for (int i = 0; i < 2; ++i) {
                const int qg = q0w + i * 16 + lr;
                float sv[16];
                if (dmask) {                          // wave-uniform branch
                    #pragma unroll
                    for (int kt = 0; kt < 4; ++kt)
                        #pragma unroll
                        for (int rr = 0; rr < 4; ++rr) {
                            float sc = st[i][kt][rr];
                            if ((k0 + kt * 16 + lg * 4 + rr) > qg) sc = -1e30f;
                            sv[kt * 4 + rr] = sc;
                        }
                } else {
                    #pragma unroll
                    for (int kt = 0; kt < 4; ++kt)
                        #pragma unroll
                        for (int rr = 0; rr < 4; ++rr)
                            sv[kt * 4 + rr] = st[i][kt][rr];
                }
                float t0 = fmaxf(fmaxf(sv[0], sv[1]), sv[2]);
                float t1 = fmaxf(fmaxf(sv[3], sv[4]), sv[5]);
                float t2 = fmaxf(fmaxf(sv[6], sv[7]), sv[8]);
                float t3 = fmaxf(fmaxf(sv[9], sv[10]), sv[11]);
                float t4 = fmaxf(fmaxf(sv[12], sv[13]), sv[14]);
                float tm = fmaxf(fmaxf(fmaxf(t0, t1), t2),
                                 fmaxf(fmaxf(t3, t4), sv[15]));
                tm = fmaxf(tm, __shfl_xor(tm, 16));
                tm = fmaxf(tm, __shfl_xor(tm, 32));
                float mnew = mrun[i];
                if (!__all(tm <= mrun[i] + 8.0f)) {      // T13 defer-max
                    mnew = fmaxf(mrun[i], tm);
                    float f = __builtin_amdgcn_exp2f(mrun[i] - mnew);
                    lrun[i] *= f;
                    #pragma unroll
                    for (int tt = 0; tt < 4; ++tt) acc[i][tt] *= f;
                    mrun[i] = mnew;
                }
                float psum = 0.0f;
                #pragma unroll
                for (int kt = 0; kt < 4; ++kt) {
                    short ph[4];
                    #pragma unroll
                    for (int rr = 0; rr < 4; ++rr) {
                        float p = __builtin_amdgcn_exp2f(sv[kt * 4 + rr] - mnew);
                        psum += p;
                        ph[rr] = fb(p);
                    }
                    pb[i][kt] = (s16x4){ ph[0], ph[1], ph[2], ph[3] };
                }
                lrun[i] += psum;                     // per-lane partial
            }

            __builtin_amdgcn_s_setprio(1);
            #pragma unroll
            for (int kt = 0; kt < 4; ++kt)
                #pragma unroll
                for (int tt = 0; tt < 4; ++tt) {
                    const int rb = (tt * 16 + lr) * 64;
                    const int gsw = (kt * 2 + (lg >> 1)) ^ r7;
                    s16x4 vf = *(const s16x4*)
                        (&Vlds[cur][rb + (gsw << 3) + ((lg & 1) << 2)]);
                    acc[0][tt] = __builtin_amdgcn_mfma_f32_16x16x16bf16_1k(
                        vf, pb[0][kt], acc[0][tt], 0, 0, 0);
                    acc[1][tt] = __builtin_amdgcn_mfma_f32_16x16x16bf16_1k(
                        vf, pb[1][kt], acc[1][tt], 0, 0, 0);
                }
            __builtin_amdgcn_s_setprio(0);
        }
        __syncthreads();
    }

    #pragma unroll
    for (int i = 0; i < 2; ++i) {
        float l = lrun[i];
        l += __shfl_xor(l, 16);
        l += __shfl_xor(l, 32);
        const float inv = 1.0f / l;
        u16* ob = Op + (((long)b * S_ + q0w + i * 16 + lr) * H_ + h) * Dh_;
        #pragma unroll
        for (int tt = 0; tt < 4; ++tt) {
            union { short h4[4]; unsigned long long u; } pk;
            #pragma unroll
            for (int rr = 0; rr < 4; ++rr) pk.h4[rr] = fb(acc[i][tt][rr] * inv);
            *(unsigned long long*)(ob + tt * 16 + lg * 4) = pk.u;
        }
    }
}

// ---------------------------------------------------------------------------
extern "C" void kernel_launch(void* const* d_in, const int* in_sizes, int n_in,
                              void* d_out, int out_size, void* d_ws, size_t ws_size,
                              hipStream_t stream)
{
    const float* q  = (const float*)d_in[0];
    const float* k  = (const float*)d_in[1];
    const float* v  = (const float*)d_in[2];
    // d_in[3] = causal mask — hardcoded
    const float* Wq = (const float*)d_in[4];
    const float* Wk = (const float*)d_in[5];
    const float* Wv = (const float*)d_in[6];
    const float* Wo = (const float*)d_in[7];

    u16* ws = (u16*)d_ws;
    const long NE = (long)B_ * S_ * D_;           // 8388608 elems
    const long WE = (long)D_ * D_;                // 1048576 elems
    u16* Qp  = ws;                                 // [B,H,S,Dh]
    u16* Kws_ = ws + NE;                           // K swizzled tiles
    u16* Vws_ = ws + 2 * NE;                       // V^T swizzled tiles
    u16* Op  = ws + 3 * NE;                        // [B,S,H,Dh]
    u16* WqB = Op;            // dead before attn writes Op
    u16* WkB = Op + WE;
    u16* WvB = Op + 2 * WE;

    // Wo-bf16: spare region past 4*NE if ws allows (single up-front cvt);
    // else fall back to Qp after attn (extra launch).
    const bool woExtra = ws_size >= (size_t)(4 * NE + WE) * 2;
    u16* WoB = woExtra ? (ws + 4 * NE) : Qp;

    dim3 blk(256);
    if (woExtra) {
        hipLaunchKernelGGL(cvtW, dim3(512, 4), blk, 0, stream,
                           Wq, Wk, Wv, Wo, WqB, WkB, WvB, WoB);
    } else {
        hipLaunchKernelGGL(cvtW, dim3(512, 3), blk, 0, stream,
                           Wq, Wk, Wv, Wo, WqB, WkB, WvB, WoB);
    }
    hipLaunchKernelGGL(gemmQKV, dim3(64, 4, 3), dim3(512), 0, stream,
                       q, k, v, WqB, WkB, WvB, Qp, Kws_, Vws_);
    hipLaunchKernelGGL(attn, dim3(1024), blk, 0, stream, Qp, Kws_, Vws_, Op);
    if (!woExtra) {
        hipLaunchKernelGGL(cvtW, dim3(512, 1), blk, 0, stream,
                           Wo, Wo, Wo, Wo, WoB, WoB, WoB, WoB);
    }
    hipLaunchKernelGGL(gemmO, dim3(64, 8), blk, 0, stream, Op, WoB, (float*)d_out);
}